// Round 1
// baseline (4591.710 us; speedup 1.0000x reference)
//
#include <hip/hip_runtime.h>

typedef unsigned short u16;
typedef __attribute__((ext_vector_type(8))) short s16x8;
typedef __attribute__((ext_vector_type(4))) float f32x4;

#define MFMA16(a, b, c) __builtin_amdgcn_mfma_f32_16x16x32_bf16((a), (b), (c), 0, 0, 0)

static constexpr int Bn = 512, Tn = 128, Dn = 128, Hn = 256;
static constexpr int NG = 4 * Hn;           // 1024 gate rows
static constexpr int KG = 2 * Dn + Hn;      // 512 gate K (c_c | m | h)
static constexpr long long BTD = (long long)Bn * Tn * Dn;

__device__ __forceinline__ u16 f2bf(float f) {
  union { float f; unsigned u; } v; v.f = f;
  unsigned u = v.u;
  return (u16)((u + 0x7fffu + ((u >> 16) & 1u)) >> 16);
}
__device__ __forceinline__ float bf2f(u16 h) {
  union { unsigned u; float f; } v; v.u = ((unsigned)h) << 16;
  return v.f;
}
__device__ __forceinline__ float sigm(float x) { return 1.f / (1.f + expf(-x)); }

// ---------------- K0: weight prepack to bf16 ----------------
__global__ void k_pack(const float* __restrict__ W_ih, const float* __restrict__ W_hh,
                       const float* __restrict__ W_hr, const float* __restrict__ W_fr,
                       const float* __restrict__ W_dh, const float* __restrict__ W_wc,
                       u16* Wg, u16* Whr_b, u16* Wfr_b, u16* Wdh_b, u16* Wwc_b) {
  int i = blockIdx.x * 256 + threadIdx.x;   // up to 524288
  if (i < NG * KG) {
    int n = i >> 9, k = i & 511;
    float v = (k < 256) ? W_ih[n * 256 + k] : W_hh[n * 256 + (k - 256)];
    Wg[i] = f2bf(v);
  }
  if (i < Dn * Hn) Whr_b[i] = f2bf(W_hr[i]);                      // [128][256]
  if (i < Dn * Dn) {                                              // [128][128], zero diag
    int r = i >> 7, c = i & 127;
    Wfr_b[i] = f2bf(r == c ? 0.f : W_fr[i]);
  }
  if (i < Hn * Dn) Wdh_b[i] = f2bf(W_dh[i]);                      // [256][128]
  if (i < Dn * Hn) Wwc_b[i] = f2bf(W_wc[i]);                      // [128][256]
}

// ---------------- K1: deltas + gamma_x + m (time-major bf16) ----------------
__global__ void k_delta(const int* __restrict__ mask, const float* __restrict__ W_dx,
                        const float* __restrict__ b_dx,
                        u16* delta_bf, u16* gx_bf, u16* m_bf) {
  int idx = blockIdx.x * 256 + threadIdx.x;  // B*D = 65536 threads
  int b = idx >> 7, d = idx & 127;
  float dxd = W_dx[d * Dn + d], bxd = b_dx[d];
  float del = 0.f;
  for (int t = 0; t < Tn; ++t) {
    long long o = ((long long)t * Bn + b) * Dn + d;
    delta_bf[o] = f2bf(del);                                       // exact (integer <= 128)
    gx_bf[o] = f2bf(expf(-fmaxf(del * dxd + bxd, 0.f)));
    float m = (float)mask[((long long)b * Tn + t) * Dn + d];
    m_bf[o] = f2bf(m);
    del = m + (1.f - m) * (del + 1.f);                             // delta[t+1] from m[t]
  }
}

// ---------------- K2: gamma_h = exp(-relu(delta @ W_dh^T + b_dh)), bf16 [T][B][H] ----------------
__global__ void k_gammah(const u16* __restrict__ delta_bf, const u16* __restrict__ Wdh_b,
                         const float* __restrict__ b_dh, u16* __restrict__ gammah) {
  int bid = blockIdx.x;                 // T * (B/16) = 4096
  int t = bid >> 5, b0 = (bid & 31) << 4;
  int tid = threadIdx.x, wid = tid >> 6, l = tid & 63;
  int lr = l & 15, lg = l >> 4;
  const u16* Arow = delta_bf + ((long long)t * Bn + b0) * Dn;
  s16x8 afr[4];
#pragma unroll
  for (int ks = 0; ks < 4; ++ks)
    afr[ks] = *(const s16x8*)(Arow + (long long)lr * Dn + ks * 32 + lg * 8);
#pragma unroll
  for (int q = 0; q < 4; ++q) {
    int n0 = (wid * 4 + q) * 16;
    f32x4 acc = {0.f, 0.f, 0.f, 0.f};
#pragma unroll
    for (int ks = 0; ks < 4; ++ks) {
      s16x8 bfr = *(const s16x8*)(Wdh_b + (long long)(n0 + lr) * Dn + ks * 32 + lg * 8);
      acc = MFMA16(afr[ks], bfr, acc);
    }
    int n = n0 + lr;
    float bb = b_dh[n];
#pragma unroll
    for (int r = 0; r < 4; ++r) {
      int row = lg * 4 + r;
      float g = expf(-fmaxf(acc[r] + bb, 0.f));
      gammah[((long long)t * Bn + b0 + row) * Hn + n] = f2bf(g);
    }
  }
}

// ---------------- K3: alpha = [gamma_x, m] @ W_wc^T + b_wc, f32 [T][B][D] ----------------
__global__ void k_alpha(const u16* __restrict__ gx_bf, const u16* __restrict__ m_bf,
                        const u16* __restrict__ Wwc_b, const float* __restrict__ b_wc,
                        float* __restrict__ alpha) {
  int bid = blockIdx.x;                 // 4096
  int t = bid >> 5, b0 = (bid & 31) << 4;
  int tid = threadIdx.x, wid = tid >> 6, l = tid & 63;
  int lr = l & 15, lg = l >> 4;
  s16x8 afr[8];
#pragma unroll
  for (int ks = 0; ks < 8; ++ks) {
    const u16* src = (ks < 4) ? gx_bf : m_bf;
    int kk = (ks & 3) * 32 + lg * 8;
    afr[ks] = *(const s16x8*)(src + ((long long)t * Bn + b0 + lr) * Dn + kk);
  }
#pragma unroll
  for (int q = 0; q < 2; ++q) {
    int n0 = (wid * 2 + q) * 16;
    f32x4 acc = {0.f, 0.f, 0.f, 0.f};
#pragma unroll
    for (int ks = 0; ks < 8; ++ks) {
      s16x8 bfr = *(const s16x8*)(Wwc_b + (long long)(n0 + lr) * (2 * Dn) + ks * 32 + lg * 8);
      acc = MFMA16(afr[ks], bfr, acc);
    }
    int n = n0 + lr;
    float bb = b_wc[n];
#pragma unroll
    for (int r = 0; r < 4; ++r)
      alpha[((long long)t * Bn + b0 + lg * 4 + r) * Dn + n] = acc[r] + bb;
  }
}

// ---------------- K4: persistent per-batch-slice scan ----------------
// 32 blocks x 1024 threads; block owns batch rows [16*bid, 16*bid+16).
// LDS A layout: k-chunk-major [chunk = k>>3][row(16)][k&7] bf16.
//   chunks 0..15  : c_c (K 0..127)
//   chunks 16..31 : m   (K 128..255)
//   chunks 32..63 : h_dec (K 256..511)
__global__ __launch_bounds__(1024) void k_main(
    const float* __restrict__ x, const int* __restrict__ mask,
    const u16* __restrict__ Wg, const u16* __restrict__ Whr_b, const u16* __restrict__ Wfr_b,
    const u16* __restrict__ gammah, const float* __restrict__ alpha,
    const float* __restrict__ b_ih, const float* __restrict__ b_hh,
    const float* __restrict__ b_hr, const float* __restrict__ b_fr,
    float* __restrict__ out) {
  __shared__ u16 A_lds[64 * 16 * 8];   // 16 KB
  __shared__ u16 Axc[16 * 16 * 8];     // 4 KB (x_c, K=128)

  const int tid = threadIdx.x, wid = tid >> 6, l = tid & 63;
  const int lr = l & 15, lg = l >> 4;
  const int b0 = blockIdx.x * 16;

  // zero h_dec chunks (h0 = 0)
  for (int i = tid; i < 32 * 16 * 8; i += 1024) A_lds[32 * 128 + i] = 0;

  // per-lane constants
  const int j = wid * 16 + lr;                        // hidden index owned at pointwise
  float bg[4];
#pragma unroll
  for (int g = 0; g < 4; ++g) bg[g] = b_ih[g * 256 + j] + b_hh[g * 256 + j];
  const int d0 = (wid < 8) ? wid * 16 : 0;
  const int dd = d0 + lr;                             // feature col for phases 1-2
  const float bhr = b_hr[dd], bfr = b_fr[dd];

  const u16* a_base = A_lds + lg * 128 + lr * 8;      // chunk-group (lg) + row(lr)
  const u16* axc_base = Axc + lg * 128 + lr * 8;

  float cst[4] = {0.f, 0.f, 0.f, 0.f};                // LSTM cell state (4 batch rows, 1 hidden)
  float xh[4], xv[4];
  int mv[4];

  float* out0 = out;
  float* out1 = out + BTD;
  float* out2 = out + 2 * BTD;
  float* out3 = out + 3 * BTD;

  for (int t = 0; t < Tn; ++t) {
    __syncthreads();  // h_dec(t) + (t>0) writes visible
    // ---- phase 1: x_h = h_dec @ W_hr^T + b_hr ; x_c ; m-pack (waves 0-7) ----
    if (wid < 8) {
      f32x4 acc = {0.f, 0.f, 0.f, 0.f};
#pragma unroll
      for (int ks = 0; ks < 8; ++ks) {
        s16x8 a = *(const s16x8*)(a_base + 32 * 128 + ks * 512);
        s16x8 b = *(const s16x8*)(Whr_b + (long long)dd * Hn + ks * 32 + lg * 8);
        acc = MFMA16(a, b, acc);
      }
#pragma unroll
      for (int r = 0; r < 4; ++r) {
        int row = lg * 4 + r;
        long long gx = ((long long)(b0 + row) * Tn + t) * Dn + dd;
        xh[r] = acc[r] + bhr;
        xv[r] = x[gx];
        mv[r] = mask[gx];
        float xc = mv[r] ? xv[r] : xh[r];
        out0[gx] = xh[r];
        Axc[(dd >> 3) * 128 + row * 8 + (dd & 7)] = f2bf(xc);
        A_lds[(16 + (dd >> 3)) * 128 + row * 8 + (dd & 7)] = f2bf((float)mv[r]);
      }
    }
    __syncthreads();  // Axc ready
    // ---- phase 2: z_h = x_c @ W_fr'^T + b_fr ; c_h ; c_c-pack (waves 0-7) ----
    if (wid < 8) {
      f32x4 acc = {0.f, 0.f, 0.f, 0.f};
#pragma unroll
      for (int ks = 0; ks < 4; ++ks) {
        s16x8 a = *(const s16x8*)(axc_base + ks * 512);
        s16x8 b = *(const s16x8*)(Wfr_b + (long long)dd * Dn + ks * 32 + lg * 8);
        acc = MFMA16(a, b, acc);
      }
#pragma unroll
      for (int r = 0; r < 4; ++r) {
        int row = lg * 4 + r;
        long long gx = ((long long)(b0 + row) * Tn + t) * Dn + dd;
        float z = acc[r] + bfr;
        float al = alpha[((long long)t * Bn + b0 + row) * Dn + dd];
        float ch = al * z + (1.f - al) * xh[r];
        float cc = mv[r] ? xv[r] : ch;
        out1[gx] = z;
        out2[gx] = ch;
        out3[gx] = ch;
        A_lds[(dd >> 3) * 128 + row * 8 + (dd & 7)] = f2bf(cc);
      }
    }
    __syncthreads();  // full A (c_c | m | h_dec) ready
    // ---- phase 3: gates GEMM, all 16 waves; wave w owns j-tile j0=16w, 4 gate tiles ----
    {
      f32x4 acc0 = {0.f, 0.f, 0.f, 0.f}, acc1 = acc0, acc2 = acc0, acc3 = acc0;
      const u16* wg0 = Wg + ((long long)(0 * 256 + j)) * KG + lg * 8;
      const u16* wg1 = Wg + ((long long)(1 * 256 + j)) * KG + lg * 8;
      const u16* wg2 = Wg + ((long long)(2 * 256 + j)) * KG + lg * 8;
      const u16* wg3 = Wg + ((long long)(3 * 256 + j)) * KG + lg * 8;
#pragma unroll 4
      for (int ks = 0; ks < 16; ++ks) {
        s16x8 a = *(const s16x8*)(a_base + ks * 512);
        s16x8 w0 = *(const s16x8*)(wg0 + ks * 32);
        s16x8 w1 = *(const s16x8*)(wg1 + ks * 32);
        s16x8 w2 = *(const s16x8*)(wg2 + ks * 32);
        s16x8 w3 = *(const s16x8*)(wg3 + ks * 32);
        acc0 = MFMA16(a, w0, acc0);
        acc1 = MFMA16(a, w1, acc1);
        acc2 = MFMA16(a, w2, acc2);
        acc3 = MFMA16(a, w3, acc3);
      }
      __syncthreads();  // everyone done READING A_lds; safe to overwrite h_dec
      // ---- pointwise LSTM, in-lane; write h_dec(t+1) ----
#pragma unroll
      for (int r = 0; r < 4; ++r) {
        int row = lg * 4 + r;
        float iv = sigm(acc0[r] + bg[0]);
        float fv = sigm(acc1[r] + bg[1]);
        float gv = tanhf(acc2[r] + bg[2]);
        float ov = sigm(acc3[r] + bg[3]);
        cst[r] = fv * cst[r] + iv * gv;
        float h = ov * tanhf(cst[r]);
        if (t + 1 < Tn) {
          float gm = bf2f(gammah[((long long)(t + 1) * Bn + b0 + row) * Hn + j]);
          A_lds[(32 + (j >> 3)) * 128 + row * 8 + (j & 7)] = f2bf(h * gm);
        }
      }
    }
  }
}

extern "C" void kernel_launch(void* const* d_in, const int* in_sizes, int n_in,
                              void* d_out, int out_size, void* d_ws, size_t ws_size,
                              hipStream_t stream) {
  (void)in_sizes; (void)n_in; (void)out_size; (void)ws_size;
  const float* x = (const float*)d_in[0];
  const int* mask = (const int*)d_in[1];
  const float* W_ih = (const float*)d_in[2];
  const float* W_hh = (const float*)d_in[3];
  const float* b_ih = (const float*)d_in[4];
  const float* b_hh = (const float*)d_in[5];
  const float* W_dh = (const float*)d_in[6];
  const float* b_dh = (const float*)d_in[7];
  const float* W_dx = (const float*)d_in[8];
  const float* b_dx = (const float*)d_in[9];
  const float* W_hr = (const float*)d_in[10];
  const float* b_hr = (const float*)d_in[11];
  const float* W_fr = (const float*)d_in[12];
  const float* b_fr = (const float*)d_in[13];
  const float* W_wc = (const float*)d_in[14];
  const float* b_wc = (const float*)d_in[15];

  char* ws = (char*)d_ws;
  size_t off = 0;
  auto alloc = [&](size_t bytes) {
    void* p = ws + off;
    off = (off + bytes + 255) & ~(size_t)255;
    return p;
  };
  const long long TBD = (long long)Tn * Bn * Dn;      // 8.4M
  const long long TBH = (long long)Tn * Bn * Hn;      // 16.8M
  u16* delta_bf = (u16*)alloc(TBD * 2);
  u16* gx_bf    = (u16*)alloc(TBD * 2);
  u16* m_bf     = (u16*)alloc(TBD * 2);
  u16* gammah   = (u16*)alloc(TBH * 2);
  float* alphaw = (float*)alloc(TBD * 4);
  u16* Wg    = (u16*)alloc((size_t)NG * KG * 2);
  u16* Whr_b = (u16*)alloc((size_t)Dn * Hn * 2);
  u16* Wfr_b = (u16*)alloc((size_t)Dn * Dn * 2);
  u16* Wdh_b = (u16*)alloc((size_t)Hn * Dn * 2);
  u16* Wwc_b = (u16*)alloc((size_t)Dn * Hn * 2);

  k_pack<<<2048, 256, 0, stream>>>(W_ih, W_hh, W_hr, W_fr, W_dh, W_wc,
                                   Wg, Whr_b, Wfr_b, Wdh_b, Wwc_b);
  k_delta<<<(Bn * Dn) / 256, 256, 0, stream>>>(mask, W_dx, b_dx, delta_bf, gx_bf, m_bf);
  k_gammah<<<Tn * (Bn / 16), 256, 0, stream>>>(delta_bf, Wdh_b, b_dh, gammah);
  k_alpha<<<Tn * (Bn / 16), 256, 0, stream>>>(gx_bf, m_bf, Wwc_b, b_wc, alphaw);
  k_main<<<Bn / 16, 1024, 0, stream>>>(x, mask, Wg, Whr_b, Wfr_b, gammah, alphaw,
                                       b_ih, b_hh, b_hr, b_fr, (float*)d_out);
}

// Round 2
// 2619.827 us; speedup vs baseline: 1.7527x; 1.7527x over previous
//
#include <hip/hip_runtime.h>

typedef unsigned short u16;
typedef unsigned long long u64;
typedef __attribute__((ext_vector_type(8))) short s16x8;
typedef __attribute__((ext_vector_type(4))) float f32x4;

#define MFMA16(a, b, c) __builtin_amdgcn_mfma_f32_16x16x32_bf16((a), (b), (c), 0, 0, 0)

static constexpr int Bn = 512, Tn = 128, Dn = 128, Hn = 256;
static constexpr int NG = 4 * Hn;           // 1024 gate rows
static constexpr int KG = 2 * Dn + Hn;      // 512 gate K (c_c | m | h)
static constexpr long long BTD = (long long)Bn * Tn * Dn;

__device__ __forceinline__ u16 f2bf(float f) {
  union { float f; unsigned u; } v; v.f = f;
  unsigned u = v.u;
  return (u16)((u + 0x7fffu + ((u >> 16) & 1u)) >> 16);
}
__device__ __forceinline__ float bf2f(u16 h) {
  union { unsigned u; float f; } v; v.u = ((unsigned)h) << 16;
  return v.f;
}
__device__ __forceinline__ float sigm(float x) { return 1.f / (1.f + expf(-x)); }

// ---------------- K0: weight prepack to bf16 ----------------
__global__ void k_pack(const float* __restrict__ W_ih, const float* __restrict__ W_hh,
                       const float* __restrict__ W_hr, const float* __restrict__ W_fr,
                       const float* __restrict__ W_dh, const float* __restrict__ W_wc,
                       u16* Wg, u16* Whr_b, u16* Wfr_b, u16* Wdh_b, u16* Wwc_b) {
  int i = blockIdx.x * 256 + threadIdx.x;   // up to 524288
  if (i < NG * KG) {
    int n = i >> 9, k = i & 511;
    float v = (k < 256) ? W_ih[n * 256 + k] : W_hh[n * 256 + (k - 256)];
    Wg[i] = f2bf(v);
  }
  if (i < Dn * Hn) Whr_b[i] = f2bf(W_hr[i]);                      // [128][256]
  if (i < Dn * Dn) {                                              // [128][128], zero diag
    int r = i >> 7, c = i & 127;
    Wfr_b[i] = f2bf(r == c ? 0.f : W_fr[i]);
  }
  if (i < Hn * Dn) Wdh_b[i] = f2bf(W_dh[i]);                      // [256][128]
  if (i < Dn * Hn) Wwc_b[i] = f2bf(W_wc[i]);                      // [128][256]
}

// ---------------- K1: deltas + gamma_x + m (time-major bf16) ----------------
__global__ void k_delta(const int* __restrict__ mask, const float* __restrict__ W_dx,
                        const float* __restrict__ b_dx,
                        u16* delta_bf, u16* gx_bf, u16* m_bf) {
  int idx = blockIdx.x * 256 + threadIdx.x;  // B*D = 65536 threads
  int b = idx >> 7, d = idx & 127;
  float dxd = W_dx[d * Dn + d], bxd = b_dx[d];
  float del = 0.f;
  for (int t = 0; t < Tn; ++t) {
    long long o = ((long long)t * Bn + b) * Dn + d;
    delta_bf[o] = f2bf(del);                                       // exact (integer <= 128)
    gx_bf[o] = f2bf(expf(-fmaxf(del * dxd + bxd, 0.f)));
    float m = (float)mask[((long long)b * Tn + t) * Dn + d];
    m_bf[o] = f2bf(m);
    del = m + (1.f - m) * (del + 1.f);                             // delta[t+1] from m[t]
  }
}

// ---------------- K2: gamma_h = exp(-relu(delta @ W_dh^T + b_dh)), bf16 [T][B][H] ----------------
__global__ void k_gammah(const u16* __restrict__ delta_bf, const u16* __restrict__ Wdh_b,
                         const float* __restrict__ b_dh, u16* __restrict__ gammah) {
  int bid = blockIdx.x;                 // T * (B/16) = 4096
  int t = bid >> 5, b0 = (bid & 31) << 4;
  int tid = threadIdx.x, wid = tid >> 6, l = tid & 63;
  int lr = l & 15, lg = l >> 4;
  const u16* Arow = delta_bf + ((long long)t * Bn + b0) * Dn;
  s16x8 afr[4];
#pragma unroll
  for (int ks = 0; ks < 4; ++ks)
    afr[ks] = *(const s16x8*)(Arow + (long long)lr * Dn + ks * 32 + lg * 8);
#pragma unroll
  for (int q = 0; q < 4; ++q) {
    int n0 = (wid * 4 + q) * 16;
    f32x4 acc = {0.f, 0.f, 0.f, 0.f};
#pragma unroll
    for (int ks = 0; ks < 4; ++ks) {
      s16x8 bfr = *(const s16x8*)(Wdh_b + (long long)(n0 + lr) * Dn + ks * 32 + lg * 8);
      acc = MFMA16(afr[ks], bfr, acc);
    }
    int n = n0 + lr;
    float bb = b_dh[n];
#pragma unroll
    for (int r = 0; r < 4; ++r) {
      int row = lg * 4 + r;
      float g = expf(-fmaxf(acc[r] + bb, 0.f));
      gammah[((long long)t * Bn + b0 + row) * Hn + n] = f2bf(g);
    }
  }
}

// ---------------- K3: alpha = [gamma_x, m] @ W_wc^T + b_wc, f32 [T][B][D] ----------------
__global__ void k_alpha(const u16* __restrict__ gx_bf, const u16* __restrict__ m_bf,
                        const u16* __restrict__ Wwc_b, const float* __restrict__ b_wc,
                        float* __restrict__ alpha) {
  int bid = blockIdx.x;                 // 4096
  int t = bid >> 5, b0 = (bid & 31) << 4;
  int tid = threadIdx.x, wid = tid >> 6, l = tid & 63;
  int lr = l & 15, lg = l >> 4;
  s16x8 afr[8];
#pragma unroll
  for (int ks = 0; ks < 8; ++ks) {
    const u16* src = (ks < 4) ? gx_bf : m_bf;
    int kk = (ks & 3) * 32 + lg * 8;
    afr[ks] = *(const s16x8*)(src + ((long long)t * Bn + b0 + lr) * Dn + kk);
  }
#pragma unroll
  for (int q = 0; q < 2; ++q) {
    int n0 = (wid * 2 + q) * 16;
    f32x4 acc = {0.f, 0.f, 0.f, 0.f};
#pragma unroll
    for (int ks = 0; ks < 8; ++ks) {
      s16x8 bfr = *(const s16x8*)(Wwc_b + (long long)(n0 + lr) * (2 * Dn) + ks * 32 + lg * 8);
      acc = MFMA16(afr[ks], bfr, acc);
    }
    int n = n0 + lr;
    float bb = b_wc[n];
#pragma unroll
    for (int r = 0; r < 4; ++r)
      alpha[((long long)t * Bn + b0 + lg * 4 + r) * Dn + n] = acc[r] + bb;
  }
}

// ---------------- K4: cooperative, weight-stationary, N-split scan ----------------
// Grid = 256 blocks x 512 threads. Block (g = bid>>3, s = bid&7):
//   - owns batch rows [16g, 16g+16) and hidden slice j in [32s, 32s+32)
//   - Wg slice (128 gate rows x K=512) held in REGISTERS (16 s16x8/lane)
//   - phases 1-2 (x_h, z_h; full D=128) computed redundantly by all 8 s-blocks
//   - gates GEMM N-sliced; pointwise: 1 thread = 1 (row, j) pair, cst in 1 reg
//   - h_dec(t+1) slice exchanged via agent-scope atomics on Hex (IC-coherent),
//     per-group arrive counter + spin (32 independent 8-block syncs)
__global__ __launch_bounds__(512, 2) void k_main(
    const float* __restrict__ x, const int* __restrict__ mask,
    const u16* __restrict__ Wg, const u16* __restrict__ Whr_b, const u16* __restrict__ Wfr_b,
    const u16* __restrict__ gammah, const float* __restrict__ alpha,
    const float* __restrict__ b_ih, const float* __restrict__ b_hh,
    const float* __restrict__ b_hr, const float* __restrict__ b_fr,
    float* __restrict__ out, u64* __restrict__ Hex, int* __restrict__ cnt) {
  __shared__ __align__(16) u16 A_lds[64 * 128];   // c_c(0..15) | m(16..31) | h_dec(32..63)
  __shared__ __align__(16) u16 Axc[16 * 128];     // x_c, K=128
  __shared__ __align__(16) float G_lds[16 * 128]; // gates [row][lq]

  const int tid = threadIdx.x, wid = tid >> 6, l = tid & 63;
  const int lr = l & 15, lg = l >> 4;
  const int g = blockIdx.x >> 3, s = blockIdx.x & 7;
  const int b0 = g * 16;

  // zero h_dec region (h0 = 0)
  for (int i = tid; i < 32 * 128; i += 512) A_lds[32 * 128 + i] = 0;

  // ---- per-wave d-tile (phases 1-2) ----
  const int dd = wid * 16 + lr;
  const float bhr = b_hr[dd], bfr = b_fr[dd];

  // ---- pointwise mapping: thread = (prow, pjj) ----
  const int prow = tid >> 5, pjj = tid & 31;
  const int pj = 32 * s + pjj;
  const float bg0 = b_ih[0 * 256 + pj] + b_hh[0 * 256 + pj];
  const float bg1 = b_ih[1 * 256 + pj] + b_hh[1 * 256 + pj];
  const float bg2 = b_ih[2 * 256 + pj] + b_hh[2 * 256 + pj];
  const float bg3 = b_ih[3 * 256 + pj] + b_hh[3 * 256 + pj];

  // ---- register-resident weight fragments ----
  s16x8 whr[8], wfr[4], wg[16];
#pragma unroll
  for (int ks = 0; ks < 8; ++ks)
    whr[ks] = *(const s16x8*)(Whr_b + (long long)dd * Hn + ks * 32 + lg * 8);
#pragma unroll
  for (int ks = 0; ks < 4; ++ks)
    wfr[ks] = *(const s16x8*)(Wfr_b + (long long)dd * Dn + ks * 32 + lg * 8);
  {
    const int q = wid >> 1;
    const long long grow = q * 256 + 32 * s + 16 * (wid & 1) + lr;  // global gate row
#pragma unroll
    for (int ks = 0; ks < 16; ++ks)
      wg[ks] = *(const s16x8*)(Wg + grow * KG + ks * 32 + lg * 8);
  }

  const u16* a_base = A_lds + lg * 128 + lr * 8;
  const u16* axc_base = Axc + lg * 128 + lr * 8;

  float cst = 0.f;                                  // cell state: 1 per thread
  float xn[4]; int mn[4]; float an[4];              // prefetch regs (t)
#pragma unroll
  for (int r = 0; r < 4; ++r) {
    int row = lg * 4 + r;
    long long gx = ((long long)(b0 + row) * Tn + 0) * Dn + dd;
    xn[r] = x[gx]; mn[r] = mask[gx];
    an[r] = alpha[((long long)0 * Bn + b0 + row) * Dn + dd];
  }

  float* out0 = out;
  float* out1 = out + BTD;
  float* out2 = out + 2 * BTD;
  float* out3 = out + 3 * BTD;

#pragma unroll 1
  for (int t = 0; t < Tn; ++t) {
    __syncthreads();  // h_dec(t) visible in LDS
    // gammah(t+1) prefetch for this step's pointwise
    float gmh = 1.f;
    if (t + 1 < Tn)
      gmh = bf2f(gammah[((long long)(t + 1) * Bn + b0 + prow) * Hn + pj]);

    // ---- phase 1: x_h = h_dec @ W_hr^T + b_hr (all 8 waves, d-tile each) ----
    f32x4 acc = {0.f, 0.f, 0.f, 0.f};
#pragma unroll
    for (int ks = 0; ks < 8; ++ks) {
      s16x8 a = *(const s16x8*)(a_base + 32 * 128 + ks * 512);
      acc = MFMA16(a, whr[ks], acc);
    }
    float xh[4], xv[4], av[4]; int mv[4];
#pragma unroll
    for (int r = 0; r < 4; ++r) {
      int row = lg * 4 + r;
      long long gx = ((long long)(b0 + row) * Tn + t) * Dn + dd;
      xh[r] = acc[r] + bhr;
      xv[r] = xn[r]; mv[r] = mn[r]; av[r] = an[r];
      float xc = mv[r] ? xv[r] : xh[r];
      if (wid == s) out0[gx] = xh[r];
      Axc[(dd >> 3) * 128 + row * 8 + (dd & 7)] = f2bf(xc);
      A_lds[(16 + (dd >> 3)) * 128 + row * 8 + (dd & 7)] = f2bf((float)mv[r]);
    }
    __syncthreads();  // x_c, m ready

    // ---- phase 2: z_h = x_c @ W_fr'^T + b_fr ----
    acc = f32x4{0.f, 0.f, 0.f, 0.f};
#pragma unroll
    for (int ks = 0; ks < 4; ++ks) {
      s16x8 a = *(const s16x8*)(axc_base + ks * 512);
      acc = MFMA16(a, wfr[ks], acc);
    }
#pragma unroll
    for (int r = 0; r < 4; ++r) {
      int row = lg * 4 + r;
      long long gx = ((long long)(b0 + row) * Tn + t) * Dn + dd;
      float z = acc[r] + bfr;
      float ch = av[r] * z + (1.f - av[r]) * xh[r];
      float ccv = mv[r] ? xv[r] : ch;
      if (wid == s) { out1[gx] = z; out2[gx] = ch; out3[gx] = ch; }
      A_lds[(dd >> 3) * 128 + row * 8 + (dd & 7)] = f2bf(ccv);
    }
    __syncthreads();  // full A (c_c | m | h_dec) ready

    // ---- phase 3: gates GEMM (wave wid owns n-tile lq=[16*wid,+16)) + t+1 prefetch ----
    if (t + 1 < Tn) {
#pragma unroll
      for (int r = 0; r < 4; ++r) {
        int row = lg * 4 + r;
        long long gx2 = ((long long)(b0 + row) * Tn + (t + 1)) * Dn + dd;
        xn[r] = x[gx2]; mn[r] = mask[gx2];
        an[r] = alpha[((long long)(t + 1) * Bn + b0 + row) * Dn + dd];
      }
    }
    acc = f32x4{0.f, 0.f, 0.f, 0.f};
#pragma unroll
    for (int ks = 0; ks < 16; ++ks) {
      s16x8 a = *(const s16x8*)(a_base + ks * 512);
      acc = MFMA16(a, wg[ks], acc);
    }
#pragma unroll
    for (int r = 0; r < 4; ++r)
      G_lds[(lg * 4 + r) * 128 + wid * 16 + lr] = acc[r];
    __syncthreads();  // gates ready; A_lds reads done

    // ---- pointwise LSTM: thread = (prow, pjj) ----
    {
      float gi = G_lds[prow * 128 + 0 * 32 + pjj] + bg0;
      float gf = G_lds[prow * 128 + 1 * 32 + pjj] + bg1;
      float gg = G_lds[prow * 128 + 2 * 32 + pjj] + bg2;
      float go = G_lds[prow * 128 + 3 * 32 + pjj] + bg3;
      float iv = sigm(gi), fv = sigm(gf), gv = tanhf(gg), ov = sigm(go);
      cst = fv * cst + iv * gv;
      float h = ov * tanhf(cst);
      if (t + 1 < Tn) {
        A_lds[(32 + (pj >> 3)) * 128 + prow * 8 + (pj & 7)] = f2bf(h * gmh);
        __syncthreads();  // h slice complete in LDS
        // export own 1 KB slice (u64 words [128*s, 128*s+128))
        const u64* hl = (const u64*)(A_lds + 32 * 128);
        u64* dst = Hex + (size_t)((t + 1) & 1) * 32768 + (size_t)g * 1024;
        if (tid < 128)
          __hip_atomic_store(dst + s * 128 + tid, hl[s * 128 + tid],
                             __ATOMIC_RELAXED, __HIP_MEMORY_SCOPE_AGENT);
        __syncthreads();  // drains each wave's stores (vmcnt) before arrive
        if (tid == 0)
          __hip_atomic_fetch_add(cnt + g, 1, __ATOMIC_RELEASE, __HIP_MEMORY_SCOPE_AGENT);
        if (wid == 0) {
          const int tgt = 8 * (t + 1);
          while (__hip_atomic_load(cnt + g, __ATOMIC_ACQUIRE, __HIP_MEMORY_SCOPE_AGENT) < tgt) {}
        }
        __syncthreads();  // all 8 slices at IC
        u64* hw = (u64*)(A_lds + 32 * 128);
        hw[tid * 2] = __hip_atomic_load(dst + tid * 2, __ATOMIC_RELAXED, __HIP_MEMORY_SCOPE_AGENT);
        hw[tid * 2 + 1] = __hip_atomic_load(dst + tid * 2 + 1, __ATOMIC_RELAXED, __HIP_MEMORY_SCOPE_AGENT);
        // loop-top barrier publishes LDS h_dec(t+1)
      }
    }
  }
}

extern "C" void kernel_launch(void* const* d_in, const int* in_sizes, int n_in,
                              void* d_out, int out_size, void* d_ws, size_t ws_size,
                              hipStream_t stream) {
  (void)in_sizes; (void)n_in; (void)out_size; (void)ws_size;
  const float* x = (const float*)d_in[0];
  const int* mask = (const int*)d_in[1];
  const float* W_ih = (const float*)d_in[2];
  const float* W_hh = (const float*)d_in[3];
  const float* b_ih = (const float*)d_in[4];
  const float* b_hh = (const float*)d_in[5];
  const float* W_dh = (const float*)d_in[6];
  const float* b_dh = (const float*)d_in[7];
  const float* W_dx = (const float*)d_in[8];
  const float* b_dx = (const float*)d_in[9];
  const float* W_hr = (const float*)d_in[10];
  const float* b_hr = (const float*)d_in[11];
  const float* W_fr = (const float*)d_in[12];
  const float* b_fr = (const float*)d_in[13];
  const float* W_wc = (const float*)d_in[14];
  const float* b_wc = (const float*)d_in[15];

  char* ws = (char*)d_ws;
  size_t off = 0;
  auto alloc = [&](size_t bytes) {
    void* p = ws + off;
    off = (off + bytes + 255) & ~(size_t)255;
    return p;
  };
  const long long TBD = (long long)Tn * Bn * Dn;      // 8.4M
  const long long TBH = (long long)Tn * Bn * Hn;      // 16.8M
  u16* delta_bf = (u16*)alloc(TBD * 2);
  u16* gx_bf    = (u16*)alloc(TBD * 2);
  u16* m_bf     = (u16*)alloc(TBD * 2);
  u16* gammah   = (u16*)alloc(TBH * 2);
  float* alphaw = (float*)alloc(TBD * 4);
  u16* Wg    = (u16*)alloc((size_t)NG * KG * 2);
  u16* Whr_b = (u16*)alloc((size_t)Dn * Hn * 2);
  u16* Wfr_b = (u16*)alloc((size_t)Dn * Dn * 2);
  u16* Wdh_b = (u16*)alloc((size_t)Hn * Dn * 2);
  u16* Wwc_b = (u16*)alloc((size_t)Dn * Hn * 2);

  // Hex (512 KB) + cnt (128 B) ALIAS delta_bf's region: k_gammah (the only
  // delta_bf reader) completes before k_main starts (stream order), and
  // k_delta rewrites delta_bf every call -> deterministic across replays.
  u64* Hex = (u64*)delta_bf;                          // 2*32*1024 u64 = 512 KB
  int* cnt = (int*)((char*)delta_bf + 2 * 32 * 1024 * 8);  // 32 ints

  k_pack<<<2048, 256, 0, stream>>>(W_ih, W_hh, W_hr, W_fr, W_dh, W_wc,
                                   Wg, Whr_b, Wfr_b, Wdh_b, Wwc_b);
  k_delta<<<(Bn * Dn) / 256, 256, 0, stream>>>(mask, W_dx, b_dx, delta_bf, gx_bf, m_bf);
  k_gammah<<<Tn * (Bn / 16), 256, 0, stream>>>(delta_bf, Wdh_b, b_dh, gammah);
  k_alpha<<<Tn * (Bn / 16), 256, 0, stream>>>(gx_bf, m_bf, Wwc_b, b_wc, alphaw);
  hipMemsetAsync(cnt, 0, 32 * sizeof(int), stream);   // sync counters: zero every launch

  void* args[] = {
    (void*)&x, (void*)&mask, (void*)&Wg, (void*)&Whr_b, (void*)&Wfr_b,
    (void*)&gammah, (void*)&alphaw, (void*)&b_ih, (void*)&b_hh,
    (void*)&b_hr, (void*)&b_fr, (void*)&d_out, (void*)&Hex, (void*)&cnt
  };
  hipLaunchCooperativeKernel((const void*)k_main, dim3(256), dim3(512), args, 0, stream);
}